// Round 5
// baseline (301.349 us; speedup 1.0000x reference)
//
#include <hip/hip_runtime.h>
#include <cstdint>
#include <cstddef>

// ---------------------------------------------------------------------------
// LSA transformer block: x += attn(LN1(x)); x += MLP(LN2(x))
// B=8, N=2048, C=256, H=8, D=32, HID=1024
// ---------------------------------------------------------------------------

typedef __bf16 bf16x8 __attribute__((ext_vector_type(8)));
typedef __bf16 bf16x4 __attribute__((ext_vector_type(4)));
typedef float  f32x4  __attribute__((ext_vector_type(4)));

#define BN_TOK   2048
#define CC       256
#define HID_DIM  1024
#define MROWS    16384   // B*N

// ws layout (bytes)
#define OFF_W    0u          // 786432 bf16 weights   (1.5 MB)
#define OFF_A    1572864u    // 16384x256 bf16        (8 MB)
#define OFF_QKV  9961472u    // 16384x768 bf16 (24 MB); later x1 fp32 (16 MB)
#define OFF_H    35127296u   // 16384x1024 bf16       (32 MB)
#define WOFF_QKV 0
#define WOFF_PRJ 196608
#define WOFF_FC1 262144
#define WOFF_FC2 524288

__device__ __forceinline__ void gload_lds16(const __bf16* g, __bf16* l) {
    __builtin_amdgcn_global_load_lds(
        (const __attribute__((address_space(1))) void*)g,
        (__attribute__((address_space(3))) void*)l, 16, 0, 0);
}

// -------------------------------- weight cvt -------------------------------
__global__ __launch_bounds__(256) void cvt_w_kernel(
    const float* __restrict__ q, const float* __restrict__ p,
    const float* __restrict__ f1, const float* __restrict__ f2,
    __bf16* __restrict__ dst)
{
    int i = (blockIdx.x * 256 + threadIdx.x) * 4;
    const float* src; int off;
    if (i < 196608)      { src = q;  off = 0; }
    else if (i < 262144) { src = p;  off = 196608; }
    else if (i < 524288) { src = f1; off = 262144; }
    else                 { src = f2; off = 524288; }
    float4 v = *(const float4*)(src + (i - off));
    bf16x4 o;
    o[0] = (__bf16)v.x; o[1] = (__bf16)v.y; o[2] = (__bf16)v.z; o[3] = (__bf16)v.w;
    *(bf16x4*)(dst + i) = o;
}

// -------------------------------- layernorm --------------------------------
__global__ __launch_bounds__(256) void ln_kernel(
    const float* __restrict__ x, const float* __restrict__ g,
    const float* __restrict__ b, __bf16* __restrict__ y)
{
    const int lane = threadIdx.x & 63;
    const int row  = blockIdx.x * 4 + (threadIdx.x >> 6);
    const float4 xv = *(const float4*)(x + (size_t)row * CC + lane * 4);
    float s  = xv.x + xv.y + xv.z + xv.w;
    float s2 = xv.x*xv.x + xv.y*xv.y + xv.z*xv.z + xv.w*xv.w;
#pragma unroll
    for (int m = 1; m < 64; m <<= 1) {
        s  += __shfl_xor(s,  m);
        s2 += __shfl_xor(s2, m);
    }
    const float mean = s * (1.0f / 256.0f);
    const float var  = fmaxf(s2 * (1.0f / 256.0f) - mean * mean, 0.0f);
    const float rstd = rsqrtf(var + 1e-5f);
    const float4 gv = *(const float4*)(g + lane * 4);
    const float4 bv = *(const float4*)(b + lane * 4);
    bf16x4 o;
    o[0] = (__bf16)((xv.x - mean) * rstd * gv.x + bv.x);
    o[1] = (__bf16)((xv.y - mean) * rstd * gv.y + bv.y);
    o[2] = (__bf16)((xv.z - mean) * rstd * gv.z + bv.z);
    o[3] = (__bf16)((xv.w - mean) * rstd * gv.w + bv.w);
    *(bf16x4*)(y + (size_t)row * CC + lane * 4) = o;
}

// -------------------------------- GEMM (m97-style 128x128) -----------------
template<int BIAS, int GELU, int RES, int OUTBF>
__global__ __launch_bounds__(256) void gemm128(
    const __bf16* __restrict__ A, const __bf16* __restrict__ W,
    const float* __restrict__ bias, const float* __restrict__ res,
    void* __restrict__ outp, int M, int N, int K)
{
    __shared__ __align__(16) __bf16 As[128 * 32];
    __shared__ __align__(16) __bf16 Bs[128 * 32];
    const int tid = threadIdx.x, lane = tid & 63, wid = tid >> 6;
    const int wr = wid >> 1, wc = wid & 1;
    const int fr = lane & 15, fg = lane >> 4;
    const int tm = blockIdx.x * 128, tn = blockIdx.y * 128;

    const int lrow = lane >> 2, lk = (lane & 3) * 8;
    const __bf16* gA = A + (size_t)(tm + wid * 32 + lrow) * K + lk;
    const __bf16* gB = W + (size_t)(tn + wid * 32 + lrow) * K + lk;
    __bf16* lA = As + wid * 1024;
    __bf16* lB = Bs + wid * 1024;
    const size_t rowK16 = (size_t)16 * K;

    f32x4 acc[4][4];
    const f32x4 vz = {0.f, 0.f, 0.f, 0.f};
#pragma unroll
    for (int mi = 0; mi < 4; ++mi)
#pragma unroll
        for (int nj = 0; nj < 4; ++nj) acc[mi][nj] = vz;

    for (int k0 = 0; k0 < K; k0 += 32) {
        gload_lds16(gA + k0,          lA);
        gload_lds16(gA + rowK16 + k0, lA + 512);
        gload_lds16(gB + k0,          lB);
        gload_lds16(gB + rowK16 + k0, lB + 512);
        __syncthreads();
        bf16x8 af[4], bfv[4];
#pragma unroll
        for (int mi = 0; mi < 4; ++mi)
            af[mi] = *(const bf16x8*)&As[(wr * 64 + mi * 16 + fr) * 32 + fg * 8];
#pragma unroll
        for (int nj = 0; nj < 4; ++nj)
            bfv[nj] = *(const bf16x8*)&Bs[(wc * 64 + nj * 16 + fr) * 32 + fg * 8];
#pragma unroll
        for (int mi = 0; mi < 4; ++mi)
#pragma unroll
            for (int nj = 0; nj < 4; ++nj)
                acc[mi][nj] = __builtin_amdgcn_mfma_f32_16x16x32_bf16(
                    af[mi], bfv[nj], acc[mi][nj], 0, 0, 0);
        __syncthreads();
    }

#pragma unroll
    for (int mi = 0; mi < 4; ++mi) {
#pragma unroll
        for (int nj = 0; nj < 4; ++nj) {
            const int col = tn + wc * 64 + nj * 16 + fr;
            float bv = 0.0f;
            if (BIAS) bv = bias[col];
#pragma unroll
            for (int r = 0; r < 4; ++r) {
                const int row = tm + wr * 64 + mi * 16 + fg * 4 + r;
                float v = acc[mi][nj][r];
                if (BIAS) v += bv;
                if (GELU) v = v * 0.5f * (1.0f + erff(v * 0.70710678118654752f));
                if (RES)  v += res[(size_t)row * N + col];
                if (OUTBF) ((__bf16*)outp)[(size_t)row * N + col] = (__bf16)v;
                else       ((float*)outp)[(size_t)row * N + col]  = v;
            }
        }
    }
}

// -------------------------------- attention --------------------------------
// Swapped-operand flash attention, no-max softmax (|S| bounded; exp safe).
// QK^T computed as mfma(K,Q) -> S^T layout: i = fr (lane-local rows!),
// j = nj*16 + fg*4 + r. P row-quads pack to bf16x4 -> b64 LDS writes into a
// XOR-swizzled [32][64] tile; PV reads them back as b128 A-fragments.
// Row-sums are lane-local scalars; one shuffle-reduce at the end.
__global__ __launch_bounds__(256) void attn_kernel(
    const __bf16* __restrict__ qkv, const float* __restrict__ scale_p,
    __bf16* __restrict__ ao)
{
    __shared__ __align__(16) __bf16 Ks[64][40];
    __shared__ __align__(16) __bf16 Vt[32][72];          // V^T: [d][j]
    __shared__ __align__(16) unsigned char PsT[4][32 * 128];  // per-wave P, swizzled

    const int tid = threadIdx.x, lane = tid & 63, wid = tid >> 6;
    const int fr = lane & 15, fg = lane >> 4;
    const int qt = blockIdx.x;             // 0..15
    const int bh = blockIdx.y;             // 0..63
    const int b = bh >> 3, h = bh & 7;
    const float c = scale_p[0] * 1.4426950408889634f;   // scale * log2(e)
    const size_t base = (size_t)b * BN_TOK * 768;
    const int hq = h * 32, hk = 256 + h * 32;
    const int ib = qt * 128 + wid * 32;    // wave's q-row base (32 rows)

    // Q fragments (B-operand: row i = fr, k = d = fg*8+e)
    bf16x8 qf[2];
    qf[0] = *(const bf16x8*)&qkv[base + (size_t)(ib + fr) * 768 + hq + fg * 8];
    qf[1] = *(const bf16x8*)&qkv[base + (size_t)(ib + 16 + fr) * 768 + hq + fg * 8];

    const f32x4 vz = {0.f, 0.f, 0.f, 0.f};
    f32x4 accd[2][2];
    accd[0][0] = vz; accd[0][1] = vz; accd[1][0] = vz; accd[1][1] = vz;
    float psum[2] = {0.f, 0.f};

    const int sj = tid >> 2, sd = (tid & 3) * 8;
    const int eperm = (tid & 3) << 1;              // V-scatter bank de-alias
    const __bf16* kptr = qkv + base + (size_t)sj * 768 + hk + sd;
    const __bf16* vptr = kptr + 256;               // hv = hk + 256

    unsigned char* pst = &PsT[wid][0];
    const int swz = (fr & 7) << 4;                 // per-row byte XOR swizzle

    for (int jt = 0; jt < 32; ++jt) {
        const int jb = jt * 64;
        __syncthreads();
        *(bf16x8*)&Ks[sj][sd] = *(const bf16x8*)kptr;
        const bf16x8 vv = *(const bf16x8*)vptr;
#pragma unroll
        for (int t = 0; t < 8; ++t) {
            const int e = t ^ eperm;
            Vt[sd + e][sj] = vv[e];
        }
        kptr += (size_t)64 * 768; vptr += (size_t)64 * 768;
        __syncthreads();

        // hoisted fragments
        bf16x8 kf[4], vb[2][2];
#pragma unroll
        for (int nj = 0; nj < 4; ++nj)
            kf[nj] = *(const bf16x8*)&Ks[nj * 16 + fr][fg * 8];
#pragma unroll
        for (int ka = 0; ka < 2; ++ka)
#pragma unroll
            for (int dh = 0; dh < 2; ++dh)
                vb[ka][dh] = *(const bf16x8*)&Vt[dh * 16 + fr][ka * 32 + fg * 8];

        const bool dmask = (jb < ib + 32) && (ib < jb + 64);

#pragma unroll
        for (int mi = 0; mi < 2; ++mi) {
            // S^T = (QK^T)^T : lane holds i = ib+mi*16+fr, j = jb+nj*16+fg*4+r
            f32x4 s[4];
#pragma unroll
            for (int nj = 0; nj < 4; ++nj)
                s[nj] = __builtin_amdgcn_mfma_f32_16x16x32_bf16(kf[nj], qf[mi], vz, 0, 0, 0);
#pragma unroll
            for (int nj = 0; nj < 4; ++nj)
#pragma unroll
                for (int r = 0; r < 4; ++r)
                    s[nj][r] = exp2f(s[nj][r] * c);
            if (dmask) {
                const int gi = ib + mi * 16 + fr;
#pragma unroll
                for (int nj = 0; nj < 4; ++nj) {
                    const int gj = jb + nj * 16 + fg * 4;
#pragma unroll
                    for (int r = 0; r < 4; ++r)
                        if (gj + r == gi) s[nj][r] = 0.f;
                }
            }
            unsigned char* pr = pst + (mi * 16 + fr) * 128;
#pragma unroll
            for (int nj = 0; nj < 4; ++nj) {
                psum[mi] += (s[nj][0] + s[nj][1]) + (s[nj][2] + s[nj][3]);
                bf16x4 pk;
                pk[0] = (__bf16)s[nj][0]; pk[1] = (__bf16)s[nj][1];
                pk[2] = (__bf16)s[nj][2]; pk[3] = (__bf16)s[nj][3];
                *(bf16x4*)(pr + ((nj * 32 + fg * 8) ^ swz)) = pk;
            }
        }
        // PV: accd[mi][dh] += P(32x64) * V(64x32)
#pragma unroll
        for (int mi = 0; mi < 2; ++mi) {
            unsigned char* pr = pst + (mi * 16 + fr) * 128;
#pragma unroll
            for (int ka = 0; ka < 2; ++ka) {
                const bf16x8 pa = *(const bf16x8*)(pr + ((ka * 64 + fg * 16) ^ swz));
#pragma unroll
                for (int dh = 0; dh < 2; ++dh)
                    accd[mi][dh] = __builtin_amdgcn_mfma_f32_16x16x32_bf16(
                        pa, vb[ka][dh], accd[mi][dh], 0, 0, 0);
            }
        }
    }

    // row-sum: reduce across the 4 fg column-groups, then broadcast to C rows
#pragma unroll
    for (int mi = 0; mi < 2; ++mi) {
        float p = psum[mi];
        p += __shfl_xor(p, 16);
        p += __shfl_xor(p, 32);
        psum[mi] = p;
    }
    float rinv[2][4];
#pragma unroll
    for (int mi = 0; mi < 2; ++mi)
#pragma unroll
        for (int r = 0; r < 4; ++r)
            rinv[mi][r] = 1.0f / __shfl(psum[mi], fg * 4 + r);

#pragma unroll
    for (int mi = 0; mi < 2; ++mi)
#pragma unroll
        for (int dh = 0; dh < 2; ++dh)
#pragma unroll
            for (int r = 0; r < 4; ++r) {
                const int i = ib + mi * 16 + fg * 4 + r;
                const float o = accd[mi][dh][r] * rinv[mi][r];
                ao[(size_t)(b * BN_TOK + i) * CC + h * 32 + dh * 16 + fr] = (__bf16)o;
            }
}

// -------------------------------- launch -----------------------------------
extern "C" void kernel_launch(void* const* d_in, const int* in_sizes, int n_in,
                              void* d_out, int out_size, void* d_ws, size_t ws_size,
                              hipStream_t stream)
{
    const float* x      = (const float*)d_in[0];
    const float* ln1_g  = (const float*)d_in[1];
    const float* ln1_b  = (const float*)d_in[2];
    const float* qkv_w  = (const float*)d_in[3];
    const float* scale  = (const float*)d_in[4];
    const float* proj_w = (const float*)d_in[5];
    const float* proj_b = (const float*)d_in[6];
    const float* ln2_g  = (const float*)d_in[7];
    const float* ln2_b  = (const float*)d_in[8];
    const float* fc1_w  = (const float*)d_in[9];
    const float* fc1_b  = (const float*)d_in[10];
    const float* fc2_w  = (const float*)d_in[11];
    const float* fc2_b  = (const float*)d_in[12];

    char* ws = (char*)d_ws;
    __bf16* wbf   = (__bf16*)(ws + OFF_W);
    __bf16* abf   = (__bf16*)(ws + OFF_A);
    __bf16* qkvbf = (__bf16*)(ws + OFF_QKV);
    float*  x1    = (float*) (ws + OFF_QKV);
    __bf16* hbf   = (__bf16*)(ws + OFF_H);
    float*  out   = (float*)d_out;

    cvt_w_kernel<<<768, 256, 0, stream>>>(qkv_w, proj_w, fc1_w, fc2_w, wbf);
    ln_kernel<<<4096, 256, 0, stream>>>(x, ln1_g, ln1_b, abf);
    gemm128<0,0,0,1><<<dim3(128,6), 256, 0, stream>>>(
        abf, wbf + WOFF_QKV, nullptr, nullptr, qkvbf, MROWS, 768, 256);
    attn_kernel<<<dim3(16,64), 256, 0, stream>>>(qkvbf, scale, abf);
    gemm128<1,0,1,0><<<dim3(128,2), 256, 0, stream>>>(
        abf, wbf + WOFF_PRJ, proj_b, x, x1, MROWS, 256, 256);
    ln_kernel<<<4096, 256, 0, stream>>>(x1, ln2_g, ln2_b, abf);
    gemm128<1,1,0,1><<<dim3(128,8), 256, 0, stream>>>(
        abf, wbf + WOFF_FC1, fc1_b, nullptr, hbf, MROWS, HID_DIM, 256);
    gemm128<1,0,1,0><<<dim3(128,2), 256, 0, stream>>>(
        hbf, wbf + WOFF_FC2, fc2_b, x1, out, MROWS, 256, HID_DIM);
}

// Round 6
// 261.770 us; speedup vs baseline: 1.1512x; 1.1512x over previous
//
#include <hip/hip_runtime.h>
#include <cstdint>
#include <cstddef>

// ---------------------------------------------------------------------------
// LSA transformer block: x += attn(LN1(x)); x += MLP(LN2(x))
// B=8, N=2048, C=256, H=8, D=32, HID=1024
// ---------------------------------------------------------------------------

typedef __bf16 bf16x8 __attribute__((ext_vector_type(8)));
typedef __bf16 bf16x4 __attribute__((ext_vector_type(4)));
typedef float  f32x4  __attribute__((ext_vector_type(4)));

#define BN_TOK   2048
#define CC       256
#define HID_DIM  1024
#define MROWS    16384   // B*N

// ws layout (bytes)
#define OFF_W    0u          // 786432 bf16 weights (1.5 MB)
#define OFF_A    1572864u    // 16384x256 bf16 (8 MB): ln1/attn/ln2 out
#define OFF_QKV  9961472u    // 16384x768 bf16 (24 MB); later x1 bf16 (8 MB)
#define OFF_H    35127296u   // vT 64x32x2048 bf16 (8 MB), then hbf 16384x1024 bf16 (32 MB)
#define WOFF_QKV 0
#define WOFF_PRJ 196608
#define WOFF_FC1 262144
#define WOFF_FC2 524288

__device__ __forceinline__ void gload_lds16(const __bf16* g, __bf16* l) {
    __builtin_amdgcn_global_load_lds(
        (const __attribute__((address_space(1))) void*)g,
        (__attribute__((address_space(3))) void*)l, 16, 0, 0);
}

// -------------------------------- weight cvt -------------------------------
__global__ __launch_bounds__(256) void cvt_w_kernel(
    const float* __restrict__ q, const float* __restrict__ p,
    const float* __restrict__ f1, const float* __restrict__ f2,
    __bf16* __restrict__ dst)
{
    int i = (blockIdx.x * 256 + threadIdx.x) * 4;
    const float* src; int off;
    if (i < 196608)      { src = q;  off = 0; }
    else if (i < 262144) { src = p;  off = 196608; }
    else if (i < 524288) { src = f1; off = 262144; }
    else                 { src = f2; off = 524288; }
    float4 v = *(const float4*)(src + (i - off));
    bf16x4 o;
    o[0] = (__bf16)v.x; o[1] = (__bf16)v.y; o[2] = (__bf16)v.z; o[3] = (__bf16)v.w;
    *(bf16x4*)(dst + i) = o;
}

// -------------------------------- layernorm (fp32 in) ----------------------
__global__ __launch_bounds__(256) void ln_kernel(
    const float* __restrict__ x, const float* __restrict__ g,
    const float* __restrict__ b, __bf16* __restrict__ y)
{
    const int lane = threadIdx.x & 63;
    const int row  = blockIdx.x * 4 + (threadIdx.x >> 6);
    const float4 xv = *(const float4*)(x + (size_t)row * CC + lane * 4);
    float s  = xv.x + xv.y + xv.z + xv.w;
    float s2 = xv.x*xv.x + xv.y*xv.y + xv.z*xv.z + xv.w*xv.w;
#pragma unroll
    for (int m = 1; m < 64; m <<= 1) {
        s  += __shfl_xor(s,  m);
        s2 += __shfl_xor(s2, m);
    }
    const float mean = s * (1.0f / 256.0f);
    const float var  = fmaxf(s2 * (1.0f / 256.0f) - mean * mean, 0.0f);
    const float rstd = rsqrtf(var + 1e-5f);
    const float4 gv = *(const float4*)(g + lane * 4);
    const float4 bv = *(const float4*)(b + lane * 4);
    bf16x4 o;
    o[0] = (__bf16)((xv.x - mean) * rstd * gv.x + bv.x);
    o[1] = (__bf16)((xv.y - mean) * rstd * gv.y + bv.y);
    o[2] = (__bf16)((xv.z - mean) * rstd * gv.z + bv.z);
    o[3] = (__bf16)((xv.w - mean) * rstd * gv.w + bv.w);
    *(bf16x4*)(y + (size_t)row * CC + lane * 4) = o;
}

// -------------------------------- layernorm (bf16 in) ----------------------
__global__ __launch_bounds__(256) void ln_bf_kernel(
    const __bf16* __restrict__ x, const float* __restrict__ g,
    const float* __restrict__ b, __bf16* __restrict__ y)
{
    const int lane = threadIdx.x & 63;
    const int row  = blockIdx.x * 4 + (threadIdx.x >> 6);
    const bf16x4 xv = *(const bf16x4*)&x[(size_t)row * CC + lane * 4];
    float x0 = (float)xv[0], x1 = (float)xv[1], x2 = (float)xv[2], x3 = (float)xv[3];
    float s  = x0 + x1 + x2 + x3;
    float s2 = x0*x0 + x1*x1 + x2*x2 + x3*x3;
#pragma unroll
    for (int m = 1; m < 64; m <<= 1) {
        s  += __shfl_xor(s,  m);
        s2 += __shfl_xor(s2, m);
    }
    const float mean = s * (1.0f / 256.0f);
    const float var  = fmaxf(s2 * (1.0f / 256.0f) - mean * mean, 0.0f);
    const float rstd = rsqrtf(var + 1e-5f);
    const float4 gv = *(const float4*)(g + lane * 4);
    const float4 bv = *(const float4*)(b + lane * 4);
    bf16x4 o;
    o[0] = (__bf16)((x0 - mean) * rstd * gv.x + bv.x);
    o[1] = (__bf16)((x1 - mean) * rstd * gv.y + bv.y);
    o[2] = (__bf16)((x2 - mean) * rstd * gv.z + bv.z);
    o[3] = (__bf16)((x3 - mean) * rstd * gv.w + bv.w);
    *(bf16x4*)(y + (size_t)row * CC + lane * 4) = o;
}

// -------------------------------- GEMM (pipelined, 3-buf) ------------------
// out[m][n] = sum_k A[m][k]*W[n][k] (+bias,+gelu,+res). BK=32.
// BM x 128 tile, 4 waves. 3-deep global_load_lds pipeline, counted vmcnt.
// VSPLIT (QKV only): blocks with tn>=512 write V transposed into vT[bh][d][n].
template<int BM, int BIAS, int GELU, int RES, int RESBF, int OUTBF, int VSPLIT>
__global__ __launch_bounds__(256) void gemm_k(
    const __bf16* __restrict__ A, const __bf16* __restrict__ W,
    const float* __restrict__ bias, const void* __restrict__ resv,
    void* __restrict__ outp, __bf16* __restrict__ vT, int M, int N, int K)
{
    constexpr int MI  = BM / 32;       // m-frags per wave
    constexpr int ASZ = BM * 32;
    __shared__ __align__(16) __bf16 As[3 * ASZ];
    __shared__ __align__(16) __bf16 Bs[3 * 4096];
    const int tid = threadIdx.x, lane = tid & 63, wid = tid >> 6;
    const int wr = wid >> 1, wc = wid & 1;
    const int fr = lane & 15, fg = lane >> 4;
    const int tm = blockIdx.x * BM, tn = blockIdx.y * 128;

    const int lrow = lane >> 2, lk = (lane & 3) * 8;
    const __bf16* gA = A + (size_t)(tm + (BM == 128 ? wid * 32 : wid * 16) + lrow) * K + lk;
    const __bf16* gB = W + (size_t)(tn + wid * 32 + lrow) * K + lk;
    const size_t rowK16 = (size_t)16 * K;
    const int aoff = (BM == 128 ? wid * 1024 : wid * 512);
    const int boff = wid * 1024;

    const int KT = K >> 5;

    auto STAGE = [&](int kt, int buf) {
        const int k0 = kt * 32;
        __bf16* lA = As + buf * ASZ + aoff;
        __bf16* lB = Bs + buf * 4096 + boff;
        gload_lds16(gA + k0, lA);
        if (BM == 128) gload_lds16(gA + rowK16 + k0, lA + 512);
        gload_lds16(gB + k0, lB);
        gload_lds16(gB + rowK16 + k0, lB + 512);
    };

    f32x4 acc[MI][4];
    const f32x4 vz = {0.f, 0.f, 0.f, 0.f};
#pragma unroll
    for (int mi = 0; mi < MI; ++mi)
#pragma unroll
        for (int nj = 0; nj < 4; ++nj) acc[mi][nj] = vz;

    STAGE(0, 0);
    STAGE(1 < KT ? 1 : 0, 1);
    if (BM == 128) asm volatile("s_waitcnt vmcnt(4)" ::: "memory");
    else           asm volatile("s_waitcnt vmcnt(3)" ::: "memory");
    __builtin_amdgcn_s_barrier();

    int cur = 0;
    for (int k = 0; k < KT; ++k) {
        int nt = k + 2; if (nt > KT - 1) nt = KT - 1;
        int sb = cur + 2; if (sb >= 3) sb -= 3;
        STAGE(nt, sb);

        const __bf16* bA = As + cur * ASZ;
        const __bf16* bB = Bs + cur * 4096;
        bf16x8 af[MI], bfv[4];
#pragma unroll
        for (int mi = 0; mi < MI; ++mi)
            af[mi] = *(const bf16x8*)&bA[(wr * (BM / 2) + mi * 16 + fr) * 32 + fg * 8];
#pragma unroll
        for (int nj = 0; nj < 4; ++nj)
            bfv[nj] = *(const bf16x8*)&bB[(wc * 64 + nj * 16 + fr) * 32 + fg * 8];
#pragma unroll
        for (int mi = 0; mi < MI; ++mi)
#pragma unroll
            for (int nj = 0; nj < 4; ++nj)
                acc[mi][nj] = __builtin_amdgcn_mfma_f32_16x16x32_bf16(
                    af[mi], bfv[nj], acc[mi][nj], 0, 0, 0);

        if (BM == 128) asm volatile("s_waitcnt vmcnt(4)" ::: "memory");
        else           asm volatile("s_waitcnt vmcnt(3)" ::: "memory");
        __builtin_amdgcn_s_barrier();
        cur += 1; if (cur == 3) cur = 0;
    }
    asm volatile("s_waitcnt vmcnt(0)" ::: "memory");

    if (VSPLIT && tn >= 512) {
        // V head -> vT[bh][d][n] transposed (quad r = 4 consecutive tokens)
#pragma unroll
        for (int mi = 0; mi < MI; ++mi) {
#pragma unroll
            for (int nj = 0; nj < 4; ++nj) {
                const int dfull = tn - 512 + wc * 64 + nj * 16 + fr;   // 0..255
                const int row0  = tm + wr * (BM / 2) + mi * 16 + fg * 4;
                const int bb = row0 >> 11;
                const int n0 = row0 & 2047;
                bf16x4 pk;
                pk[0] = (__bf16)acc[mi][nj][0]; pk[1] = (__bf16)acc[mi][nj][1];
                pk[2] = (__bf16)acc[mi][nj][2]; pk[3] = (__bf16)acc[mi][nj][3];
                *(bf16x4*)&vT[((size_t)(bb * 8 + (dfull >> 5)) * 32 + (dfull & 31)) * 2048 + n0] = pk;
            }
        }
        return;
    }

#pragma unroll
    for (int mi = 0; mi < MI; ++mi) {
#pragma unroll
        for (int nj = 0; nj < 4; ++nj) {
            const int col = tn + wc * 64 + nj * 16 + fr;
            float bv = 0.0f;
            if (BIAS) bv = bias[col];
#pragma unroll
            for (int r = 0; r < 4; ++r) {
                const int row = tm + wr * (BM / 2) + mi * 16 + fg * 4 + r;
                float v = acc[mi][nj][r];
                if (BIAS) v += bv;
                if (GELU) v = v * 0.5f * (1.0f + erff(v * 0.70710678118654752f));
                if (RES) {
                    if (RESBF) v += (float)((const __bf16*)resv)[(size_t)row * N + col];
                    else       v += ((const float*)resv)[(size_t)row * N + col];
                }
                if (OUTBF) ((__bf16*)outp)[(size_t)row * N + col] = (__bf16)v;
                else       ((float*)outp)[(size_t)row * N + col]  = v;
            }
        }
    }
}

// -------------------------------- attention --------------------------------
// Swapped-operand flash attention, no-max softmax. K and V^T staged via
// global_load_lds (3-deep pipeline, counted vmcnt, one barrier/tile).
// Read-side XOR swizzles via per-lane source permutation. Row-sums via
// ones-vector MFMA (accp) -- no per-tile VALU reduction.
__global__ __launch_bounds__(256) void attn_kernel(
    const __bf16* __restrict__ qkv, const __bf16* __restrict__ vT,
    const float* __restrict__ scale_p, __bf16* __restrict__ ao)
{
    __shared__ __align__(16) __bf16 Ks[3 * 2048];             // [buf][64 rows][32]
    __shared__ __align__(16) __bf16 Vs[3 * 2048];             // [buf][32 d][64 j]
    __shared__ __align__(16) unsigned char PsT[4][4096];      // per-wave P, swizzled

    const int tid = threadIdx.x, lane = tid & 63, wid = tid >> 6;
    const int fr = lane & 15, fg = lane >> 4;
    const int qt = blockIdx.x;             // 0..15
    const int bh = blockIdx.y;             // 0..63
    const int b = bh >> 3, h = bh & 7;
    const float c = scale_p[0] * 1.4426950408889634f;   // scale * log2(e)
    const size_t base = (size_t)b * BN_TOK * 768;
    const int hq = h * 32, hk = 256 + h * 32;
    const int ib = qt * 128 + wid * 32;    // wave's q-row base (32 rows)

    // Q fragments (B-operand: i = fr, k = d = fg*8+e), pre-scaled by c
    const bf16x8 q0 = *(const bf16x8*)&qkv[base + (size_t)(ib + fr) * 768 + hq + fg * 8];
    const bf16x8 q1 = *(const bf16x8*)&qkv[base + (size_t)(ib + 16 + fr) * 768 + hq + fg * 8];
    bf16x8 qf[2];
#pragma unroll
    for (int e = 0; e < 8; ++e) {
        qf[0][e] = (__bf16)((float)q0[e] * c);
        qf[1][e] = (__bf16)((float)q1[e] * c);
    }
    bf16x8 onesb;
#pragma unroll
    for (int e = 0; e < 8; ++e) onesb[e] = (__bf16)1.0f;

    const f32x4 vz = {0.f, 0.f, 0.f, 0.f};
    f32x4 accd[2][2];
    accd[0][0] = vz; accd[0][1] = vz; accd[1][0] = vz; accd[1][1] = vz;
    f32x4 accp[2]; accp[0] = vz; accp[1] = vz;

    // staging source addresses (per-lane; XOR block permutation baked in)
    const int srow = tid >> 2;                              // K tile row 0..63
    const int kblk = ((tid & 3) ^ (srow & 3)) * 8;
    const __bf16* ksrc = qkv + base + (size_t)srow * 768 + hk + kblk;
    const int vd   = tid >> 3;                              // V^T row d 0..31
    const int vblk = ((tid & 7) ^ (vd & 7)) * 8;
    const __bf16* vsrc = vT + ((size_t)(bh * 32 + vd)) * 2048 + vblk;
    __bf16* kdw = Ks + wid * 512;
    __bf16* vdw = Vs + wid * 512;

    auto STAGE = [&](int nt, int buf) {
        gload_lds16(ksrc + (size_t)nt * 64 * 768, kdw + buf * 2048);
        gload_lds16(vsrc + nt * 64,               vdw + buf * 2048);
    };

    unsigned char* pst = &PsT[wid][0];
    const int swz = (fr & 7) << 4;                 // per-row 16B-block XOR

    STAGE(0, 0);
    STAGE(1, 1);
    asm volatile("s_waitcnt vmcnt(2)" ::: "memory");
    __builtin_amdgcn_s_barrier();

    int cur = 0;
    for (int jt = 0; jt < 32; ++jt) {
        const int jb = jt * 64;
        int nt = jt + 2; if (nt > 31) nt = 31;
        int sb = cur + 2; if (sb >= 3) sb -= 3;
        STAGE(nt, sb);

        const __bf16* kb = Ks + cur * 2048;
        const __bf16* vbuf = Vs + cur * 2048;
        bf16x8 kf[4], vb[2][2];
#pragma unroll
        for (int nj = 0; nj < 4; ++nj)
            kf[nj] = *(const bf16x8*)&kb[(nj * 16 + fr) * 32 + ((fg ^ (fr & 3)) * 8)];
#pragma unroll
        for (int ka = 0; ka < 2; ++ka)
#pragma unroll
            for (int dh = 0; dh < 2; ++dh)
                vb[ka][dh] = *(const bf16x8*)&vbuf[(dh * 16 + fr) * 64 + (((ka * 4 + fg) ^ (fr & 7)) * 8)];

        const bool dmask = (jb < ib + 32) && (ib < jb + 64);

#pragma unroll
        for (int mi = 0; mi < 2; ++mi) {
            // S^T: lane holds i = ib+mi*16+fr, j = jb+nj*16+fg*4+r
            f32x4 s[4];
#pragma unroll
            for (int nj = 0; nj < 4; ++nj)
                s[nj] = __builtin_amdgcn_mfma_f32_16x16x32_bf16(kf[nj], qf[mi], vz, 0, 0, 0);
#pragma unroll
            for (int nj = 0; nj < 4; ++nj)
#pragma unroll
                for (int r = 0; r < 4; ++r)
                    s[nj][r] = exp2f(s[nj][r]);
            if (dmask) {
                const int gi = ib + mi * 16 + fr;
#pragma unroll
                for (int nj = 0; nj < 4; ++nj) {
                    const int gj = jb + nj * 16 + fg * 4;
#pragma unroll
                    for (int r = 0; r < 4; ++r)
                        if (gj + r == gi) s[nj][r] = 0.f;
                }
            }
            unsigned char* pr = pst + (mi * 16 + fr) * 128;
#pragma unroll
            for (int nj = 0; nj < 4; ++nj) {
                bf16x4 pk;
                pk[0] = (__bf16)s[nj][0]; pk[1] = (__bf16)s[nj][1];
                pk[2] = (__bf16)s[nj][2]; pk[3] = (__bf16)s[nj][3];
                *(bf16x4*)(pr + ((nj * 32 + fg * 8) ^ swz)) = pk;
            }
        }
        // PV + row-sum (ones) MFMA
#pragma unroll
        for (int mi = 0; mi < 2; ++mi) {
            unsigned char* pr = pst + (mi * 16 + fr) * 128;
#pragma unroll
            for (int ka = 0; ka < 2; ++ka) {
                const bf16x8 pa = *(const bf16x8*)(pr + ((ka * 64 + fg * 16) ^ swz));
#pragma unroll
                for (int dh = 0; dh < 2; ++dh)
                    accd[mi][dh] = __builtin_amdgcn_mfma_f32_16x16x32_bf16(
                        pa, vb[ka][dh], accd[mi][dh], 0, 0, 0);
                accp[mi] = __builtin_amdgcn_mfma_f32_16x16x32_bf16(
                    pa, onesb, accp[mi], 0, 0, 0);
            }
        }
        asm volatile("s_waitcnt vmcnt(2)" ::: "memory");
        __builtin_amdgcn_s_barrier();
        cur += 1; if (cur == 3) cur = 0;
    }
    asm volatile("s_waitcnt vmcnt(0)" ::: "memory");

    // accp[mi][r] = full row sum for i = ib+mi*16+fg*4+r (replicated over fr)
#pragma unroll
    for (int mi = 0; mi < 2; ++mi)
#pragma unroll
        for (int dh = 0; dh < 2; ++dh)
#pragma unroll
            for (int r = 0; r < 4; ++r) {
                const int i = ib + mi * 16 + fg * 4 + r;
                const float o = accd[mi][dh][r] / accp[mi][r];
                ao[(size_t)(b * BN_TOK + i) * CC + h * 32 + dh * 16 + fr] = (__bf16)o;
            }
}

// -------------------------------- launch -----------------------------------
extern "C" void kernel_launch(void* const* d_in, const int* in_sizes, int n_in,
                              void* d_out, int out_size, void* d_ws, size_t ws_size,
                              hipStream_t stream)
{
    const float* x      = (const float*)d_in[0];
    const float* ln1_g  = (const float*)d_in[1];
    const float* ln1_b  = (const float*)d_in[2];
    const float* qkv_w  = (const float*)d_in[3];
    const float* scale  = (const float*)d_in[4];
    const float* proj_w = (const float*)d_in[5];
    const float* proj_b = (const float*)d_in[6];
    const float* ln2_g  = (const float*)d_in[7];
    const float* ln2_b  = (const float*)d_in[8];
    const float* fc1_w  = (const float*)d_in[9];
    const float* fc1_b  = (const float*)d_in[10];
    const float* fc2_w  = (const float*)d_in[11];
    const float* fc2_b  = (const float*)d_in[12];

    char* ws = (char*)d_ws;
    __bf16* wbf   = (__bf16*)(ws + OFF_W);
    __bf16* abf   = (__bf16*)(ws + OFF_A);
    __bf16* qkvbf = (__bf16*)(ws + OFF_QKV);
    __bf16* x1bf  = (__bf16*)(ws + OFF_QKV);   // overlays qkv after attention
    __bf16* vT    = (__bf16*)(ws + OFF_H);     // 8 MB; overwritten by hbf later
    __bf16* hbf   = (__bf16*)(ws + OFF_H);
    float*  out   = (float*)d_out;

    cvt_w_kernel<<<768, 256, 0, stream>>>(qkv_w, proj_w, fc1_w, fc2_w, wbf);
    ln_kernel<<<4096, 256, 0, stream>>>(x, ln1_g, ln1_b, abf);
    gemm_k<128,0,0,0,0,1,1><<<dim3(128,6), 256, 0, stream>>>(
        abf, wbf + WOFF_QKV, nullptr, nullptr, qkvbf, vT, MROWS, 768, 256);
    attn_kernel<<<dim3(16,64), 256, 0, stream>>>(qkvbf, vT, scale, abf);
    gemm_k<64,1,0,1,0,1,0><<<dim3(256,2), 256, 0, stream>>>(
        abf, wbf + WOFF_PRJ, proj_b, x, x1bf, nullptr, MROWS, 256, 256);
    ln_bf_kernel<<<4096, 256, 0, stream>>>(x1bf, ln2_g, ln2_b, abf);
    gemm_k<128,1,1,0,0,1,0><<<dim3(128,8), 256, 0, stream>>>(
        abf, wbf + WOFF_FC1, fc1_b, nullptr, hbf, nullptr, MROWS, HID_DIM, 256);
    gemm_k<64,1,0,1,1,0,0><<<dim3(256,2), 256, 0, stream>>>(
        hbf, wbf + WOFF_FC2, fc2_b, x1bf, out, nullptr, MROWS, 256, HID_DIM);
}

// Round 7
// 247.857 us; speedup vs baseline: 1.2158x; 1.0561x over previous
//
#include <hip/hip_runtime.h>
#include <cstdint>
#include <cstddef>

// ---------------------------------------------------------------------------
// LSA transformer block: x += attn(LN1(x)); x += MLP(LN2(x))
// B=8, N=2048, C=256, H=8, D=32, HID=1024
// ---------------------------------------------------------------------------

typedef __bf16 bf16x8 __attribute__((ext_vector_type(8)));
typedef __bf16 bf16x4 __attribute__((ext_vector_type(4)));
typedef float  f32x4  __attribute__((ext_vector_type(4)));
typedef float  f32x16 __attribute__((ext_vector_type(16)));

#define BN_TOK   2048
#define CC       256
#define HID_DIM  1024
#define MROWS    16384   // B*N

// ws layout (bytes)
#define OFF_W    0u          // 786432 bf16 weights (1.5 MB)
#define OFF_A    1572864u    // 16384x256 bf16 (8 MB): ln1/attn/ln2 out
#define OFF_QKV  9961472u    // 16384x768 bf16 (24 MB); later x1 bf16 (8 MB)
#define OFF_H    35127296u   // vT 64x32x2048 bf16 (8 MB), then hbf 16384x1024 bf16 (32 MB)
#define WOFF_QKV 0
#define WOFF_PRJ 196608
#define WOFF_FC1 262144
#define WOFF_FC2 524288

__device__ __forceinline__ void gload_lds16(const __bf16* g, __bf16* l) {
    __builtin_amdgcn_global_load_lds(
        (const __attribute__((address_space(1))) void*)g,
        (__attribute__((address_space(3))) void*)l, 16, 0, 0);
}

__device__ __forceinline__ float fexp2(float x) {
    float r;
    asm("v_exp_f32 %0, %1" : "=v"(r) : "v"(x));
    return r;
}

__device__ __forceinline__ unsigned pk2(float lo, float hi) {
    union { __bf16 b[2]; unsigned u; } t;
    t.b[0] = (__bf16)lo; t.b[1] = (__bf16)hi;
    return t.u;
}

// -------------------------------- weight cvt -------------------------------
__global__ __launch_bounds__(256) void cvt_w_kernel(
    const float* __restrict__ q, const float* __restrict__ p,
    const float* __restrict__ f1, const float* __restrict__ f2,
    __bf16* __restrict__ dst)
{
    int i = (blockIdx.x * 256 + threadIdx.x) * 4;
    const float* src; int off;
    if (i < 196608)      { src = q;  off = 0; }
    else if (i < 262144) { src = p;  off = 196608; }
    else if (i < 524288) { src = f1; off = 262144; }
    else                 { src = f2; off = 524288; }
    float4 v = *(const float4*)(src + (i - off));
    bf16x4 o;
    o[0] = (__bf16)v.x; o[1] = (__bf16)v.y; o[2] = (__bf16)v.z; o[3] = (__bf16)v.w;
    *(bf16x4*)(dst + i) = o;
}

// -------------------------------- layernorm (fp32 in) ----------------------
__global__ __launch_bounds__(256) void ln_kernel(
    const float* __restrict__ x, const float* __restrict__ g,
    const float* __restrict__ b, __bf16* __restrict__ y)
{
    const int lane = threadIdx.x & 63;
    const int row  = blockIdx.x * 4 + (threadIdx.x >> 6);
    const float4 xv = *(const float4*)(x + (size_t)row * CC + lane * 4);
    float s  = xv.x + xv.y + xv.z + xv.w;
    float s2 = xv.x*xv.x + xv.y*xv.y + xv.z*xv.z + xv.w*xv.w;
#pragma unroll
    for (int m = 1; m < 64; m <<= 1) {
        s  += __shfl_xor(s,  m);
        s2 += __shfl_xor(s2, m);
    }
    const float mean = s * (1.0f / 256.0f);
    const float var  = fmaxf(s2 * (1.0f / 256.0f) - mean * mean, 0.0f);
    const float rstd = rsqrtf(var + 1e-5f);
    const float4 gv = *(const float4*)(g + lane * 4);
    const float4 bv = *(const float4*)(b + lane * 4);
    bf16x4 o;
    o[0] = (__bf16)((xv.x - mean) * rstd * gv.x + bv.x);
    o[1] = (__bf16)((xv.y - mean) * rstd * gv.y + bv.y);
    o[2] = (__bf16)((xv.z - mean) * rstd * gv.z + bv.z);
    o[3] = (__bf16)((xv.w - mean) * rstd * gv.w + bv.w);
    *(bf16x4*)(y + (size_t)row * CC + lane * 4) = o;
}

// -------------------------------- layernorm (bf16 in) ----------------------
__global__ __launch_bounds__(256) void ln_bf_kernel(
    const __bf16* __restrict__ x, const float* __restrict__ g,
    const float* __restrict__ b, __bf16* __restrict__ y)
{
    const int lane = threadIdx.x & 63;
    const int row  = blockIdx.x * 4 + (threadIdx.x >> 6);
    const bf16x4 xv = *(const bf16x4*)&x[(size_t)row * CC + lane * 4];
    float x0 = (float)xv[0], x1 = (float)xv[1], x2 = (float)xv[2], x3 = (float)xv[3];
    float s  = x0 + x1 + x2 + x3;
    float s2 = x0*x0 + x1*x1 + x2*x2 + x3*x3;
#pragma unroll
    for (int m = 1; m < 64; m <<= 1) {
        s  += __shfl_xor(s,  m);
        s2 += __shfl_xor(s2, m);
    }
    const float mean = s * (1.0f / 256.0f);
    const float var  = fmaxf(s2 * (1.0f / 256.0f) - mean * mean, 0.0f);
    const float rstd = rsqrtf(var + 1e-5f);
    const float4 gv = *(const float4*)(g + lane * 4);
    const float4 bv = *(const float4*)(b + lane * 4);
    bf16x4 o;
    o[0] = (__bf16)((x0 - mean) * rstd * gv.x + bv.x);
    o[1] = (__bf16)((x1 - mean) * rstd * gv.y + bv.y);
    o[2] = (__bf16)((x2 - mean) * rstd * gv.z + bv.z);
    o[3] = (__bf16)((x3 - mean) * rstd * gv.w + bv.w);
    *(bf16x4*)(y + (size_t)row * CC + lane * 4) = o;
}

// -------------------------------- GEMM (pipelined, 3-buf) ------------------
// out[m][n] = sum_k A[m][k]*W[n][k] (+bias,+gelu,+res). BK=32.
// BM x 128 tile, 4 waves. 3-deep global_load_lds pipeline, counted vmcnt.
// VSPLIT (QKV only): blocks with tn>=512 write V transposed into vT[bh][d][n].
template<int BM, int BIAS, int GELU, int RES, int RESBF, int OUTBF, int VSPLIT>
__global__ __launch_bounds__(256) void gemm_k(
    const __bf16* __restrict__ A, const __bf16* __restrict__ W,
    const float* __restrict__ bias, const void* __restrict__ resv,
    void* __restrict__ outp, __bf16* __restrict__ vT, int M, int N, int K)
{
    constexpr int MI  = BM / 32;       // m-frags per wave
    constexpr int ASZ = BM * 32;
    __shared__ __align__(16) __bf16 As[3 * ASZ];
    __shared__ __align__(16) __bf16 Bs[3 * 4096];
    const int tid = threadIdx.x, lane = tid & 63, wid = tid >> 6;
    const int wr = wid >> 1, wc = wid & 1;
    const int fr = lane & 15, fg = lane >> 4;
    const int tm = blockIdx.x * BM, tn = blockIdx.y * 128;

    const int lrow = lane >> 2, lk = (lane & 3) * 8;
    const __bf16* gA = A + (size_t)(tm + (BM == 128 ? wid * 32 : wid * 16) + lrow) * K + lk;
    const __bf16* gB = W + (size_t)(tn + wid * 32 + lrow) * K + lk;
    const size_t rowK16 = (size_t)16 * K;
    const int aoff = (BM == 128 ? wid * 1024 : wid * 512);
    const int boff = wid * 1024;

    const int KT = K >> 5;

    auto STAGE = [&](int kt, int buf) {
        const int k0 = kt * 32;
        __bf16* lA = As + buf * ASZ + aoff;
        __bf16* lB = Bs + buf * 4096 + boff;
        gload_lds16(gA + k0, lA);
        if (BM == 128) gload_lds16(gA + rowK16 + k0, lA + 512);
        gload_lds16(gB + k0, lB);
        gload_lds16(gB + rowK16 + k0, lB + 512);
    };

    f32x4 acc[MI][4];
    const f32x4 vz = {0.f, 0.f, 0.f, 0.f};
#pragma unroll
    for (int mi = 0; mi < MI; ++mi)
#pragma unroll
        for (int nj = 0; nj < 4; ++nj) acc[mi][nj] = vz;

    STAGE(0, 0);
    STAGE(1 < KT ? 1 : 0, 1);
    if (BM == 128) asm volatile("s_waitcnt vmcnt(4)" ::: "memory");
    else           asm volatile("s_waitcnt vmcnt(3)" ::: "memory");
    __builtin_amdgcn_s_barrier();

    int cur = 0;
    for (int k = 0; k < KT; ++k) {
        int nt = k + 2; if (nt > KT - 1) nt = KT - 1;
        int sb = cur + 2; if (sb >= 3) sb -= 3;
        STAGE(nt, sb);

        const __bf16* bA = As + cur * ASZ;
        const __bf16* bB = Bs + cur * 4096;
        bf16x8 af[MI], bfv[4];
#pragma unroll
        for (int mi = 0; mi < MI; ++mi)
            af[mi] = *(const bf16x8*)&bA[(wr * (BM / 2) + mi * 16 + fr) * 32 + fg * 8];
#pragma unroll
        for (int nj = 0; nj < 4; ++nj)
            bfv[nj] = *(const bf16x8*)&bB[(wc * 64 + nj * 16 + fr) * 32 + fg * 8];
#pragma unroll
        for (int mi = 0; mi < MI; ++mi)
#pragma unroll
            for (int nj = 0; nj < 4; ++nj)
                acc[mi][nj] = __builtin_amdgcn_mfma_f32_16x16x32_bf16(
                    af[mi], bfv[nj], acc[mi][nj], 0, 0, 0);

        if (BM == 128) asm volatile("s_waitcnt vmcnt(4)" ::: "memory");
        else           asm volatile("s_waitcnt vmcnt(3)" ::: "memory");
        __builtin_amdgcn_s_barrier();
        cur += 1; if (cur == 3) cur = 0;
    }
    asm volatile("s_waitcnt vmcnt(0)" ::: "memory");

    if (VSPLIT && tn >= 512) {
        // V head -> vT[bh][d][n] transposed (quad r = 4 consecutive tokens)
#pragma unroll
        for (int mi = 0; mi < MI; ++mi) {
#pragma unroll
            for (int nj = 0; nj < 4; ++nj) {
                const int dfull = tn - 512 + wc * 64 + nj * 16 + fr;   // 0..255
                const int row0  = tm + wr * (BM / 2) + mi * 16 + fg * 4;
                const int bb = row0 >> 11;
                const int n0 = row0 & 2047;
                bf16x4 pk;
                pk[0] = (__bf16)acc[mi][nj][0]; pk[1] = (__bf16)acc[mi][nj][1];
                pk[2] = (__bf16)acc[mi][nj][2]; pk[3] = (__bf16)acc[mi][nj][3];
                *(bf16x4*)&vT[((size_t)(bb * 8 + (dfull >> 5)) * 32 + (dfull & 31)) * 2048 + n0] = pk;
            }
        }
        return;
    }

#pragma unroll
    for (int mi = 0; mi < MI; ++mi) {
#pragma unroll
        for (int nj = 0; nj < 4; ++nj) {
            const int col = tn + wc * 64 + nj * 16 + fr;
            float bv = 0.0f;
            if (BIAS) bv = bias[col];
#pragma unroll
            for (int r = 0; r < 4; ++r) {
                const int row = tm + wr * (BM / 2) + mi * 16 + fg * 4 + r;
                float v = acc[mi][nj][r];
                if (BIAS) v += bv;
                if (GELU) v = v * 0.5f * (1.0f + erff(v * 0.70710678118654752f));
                if (RES) {
                    if (RESBF) v += (float)((const __bf16*)resv)[(size_t)row * N + col];
                    else       v += ((const float*)resv)[(size_t)row * N + col];
                }
                if (OUTBF) ((__bf16*)outp)[(size_t)row * N + col] = (__bf16)v;
                else       ((float*)outp)[(size_t)row * N + col]  = v;
            }
        }
    }
}

// -------------------------------- attention --------------------------------
// 32x32x16-MFMA flash attention, no-max softmax, P fully in-register:
// S^T = mfma32(K,Q) -> lane holds col i=lane&31, rows j per reg. After exp,
// pack pairs to bf16 dwords; 4 v_permlane32_swap redistribute P into the PV
// A-fragment layout (T12). Row sums via ones-MFMA (matches accd reg layout).
// K/V^T staged by global_load_lds, 3-buf, counted vmcnt, 1 barrier/tile.
__global__ __launch_bounds__(256) void attn_kernel(
    const __bf16* __restrict__ qkv, const __bf16* __restrict__ vT,
    const float* __restrict__ scale_p, __bf16* __restrict__ ao)
{
    __shared__ __align__(16) __bf16 Ks[3 * 2048];   // [buf][64 j][4 slots*16B], slot^=(j&3)
    __shared__ __align__(16) __bf16 Vs[3 * 2048];   // [buf][32 d][8 slots*16B], slot^=(d&7)

    const int tid = threadIdx.x, lane = tid & 63, wid = tid >> 6;
    const int l31 = lane & 31, hi = lane >> 5;
    const int qt = blockIdx.x, bh = blockIdx.y;
    const int b = bh >> 3, h = bh & 7;
    const float c = scale_p[0] * 1.4426950408889634f;   // scale * log2(e)
    const size_t base = (size_t)b * BN_TOK * 768;
    const int hq = h * 32, hk = 256 + h * 32;
    const int ib = qt * 128 + wid * 32;    // wave's 32 q-rows

    // Q B-operand (col i=l31, k = sl*16 + hi*8 + e), pre-scaled by c
    const __bf16* qrow = qkv + base + (size_t)(ib + l31) * 768 + hq;
    bf16x8 qf[2];
    {
        const bf16x8 t0 = *(const bf16x8*)(qrow + hi * 8);
        const bf16x8 t1 = *(const bf16x8*)(qrow + 16 + hi * 8);
#pragma unroll
        for (int e = 0; e < 8; ++e) {
            qf[0][e] = (__bf16)((float)t0[e] * c);
            qf[1][e] = (__bf16)((float)t1[e] * c);
        }
    }
    bf16x8 onesb;
#pragma unroll
    for (int e = 0; e < 8; ++e) onesb[e] = (__bf16)1.0f;

    f32x16 accd = {};   // O[i][d]: d = l31, i = (r&3)+8*(r>>2)+4*hi
    f32x16 accp = {};   // row sums, same layout

    // staging sources (source-baked XOR swizzles; LDS dest linear lane*16)
    const int srow = tid >> 2;
    const int kblk = ((tid & 3) ^ (srow & 3)) * 8;
    const __bf16* ksrc = qkv + base + (size_t)srow * 768 + hk + kblk;
    const int vd = tid >> 3;
    const int vblk = ((tid & 7) ^ (vd & 7)) * 8;
    const __bf16* vsrc = vT + ((size_t)(bh * 32 + vd)) * 2048 + vblk;
    __bf16* kdw = Ks + wid * 512;
    __bf16* vdw = Vs + wid * 512;

    auto STAGE = [&](int nt, int buf) {
        gload_lds16(ksrc + (size_t)nt * 64 * 768, kdw + buf * 2048);
        gload_lds16(vsrc + nt * 64,               vdw + buf * 2048);
    };

    STAGE(0, 0);
    STAGE(1, 1);
    asm volatile("s_waitcnt vmcnt(2)" ::: "memory");
    __builtin_amdgcn_s_barrier();

    int cur = 0;
    for (int jt = 0; jt < 32; ++jt) {
        const int jb = jt * 64;
        int nt = jt + 2; if (nt > 31) nt = 31;
        int sb = cur + 2; if (sb >= 3) sb -= 3;
        STAGE(nt, sb);

        const char* kb   = (const char*)(Ks + cur * 2048);
        const char* vbuf = (const char*)(Vs + cur * 2048);

        // V B-frags: row d = l31, slot = (sub*4 + ka*2 + hi) ^ (d&7)
        bf16x8 vb[2][2];
#pragma unroll
        for (int sub = 0; sub < 2; ++sub)
#pragma unroll
            for (int ka = 0; ka < 2; ++ka)
                vb[sub][ka] = *(const bf16x8*)(vbuf + l31 * 128 +
                                (((sub * 4 + ka * 2 + hi) ^ (l31 & 7)) << 4));

#pragma unroll
        for (int sub = 0; sub < 2; ++sub) {
            const int jrow = sub * 32 + l31;
            const bf16x8 kf0 = *(const bf16x8*)(kb + jrow * 64 + (((hi)     ^ (jrow & 3)) << 4));
            const bf16x8 kf1 = *(const bf16x8*)(kb + jrow * 64 + (((2 + hi) ^ (jrow & 3)) << 4));
            f32x16 s = {};
            s = __builtin_amdgcn_mfma_f32_32x32x16_bf16(kf0, qf[0], s, 0, 0, 0);
            s = __builtin_amdgcn_mfma_f32_32x32x16_bf16(kf1, qf[1], s, 0, 0, 0);
#pragma unroll
            for (int r = 0; r < 16; ++r) s[r] = fexp2(s[r]);
            if (jb + sub * 32 == ib) {   // diagonal subtile: mask j==i
#pragma unroll
                for (int r = 0; r < 16; ++r)
                    if (((r & 3) + 8 * (r >> 2) + 4 * hi) == l31) s[r] = 0.f;
            }
            // pack pairs: dw[q][h] = bf16x2 of j' = 8q+4hi+2h, +1
            unsigned dw[4][2];
#pragma unroll
            for (int q = 0; q < 4; ++q)
#pragma unroll
                for (int hh = 0; hh < 2; ++hh)
                    dw[q][hh] = pk2(s[4 * q + 2 * hh], s[4 * q + 2 * hh + 1]);
#pragma unroll
            for (int ka = 0; ka < 2; ++ka) {
                asm("v_permlane32_swap_b32 %0, %1"
                    : "+v"(dw[2 * ka][0]), "+v"(dw[2 * ka + 1][0]));
                asm("v_permlane32_swap_b32 %0, %1"
                    : "+v"(dw[2 * ka][1]), "+v"(dw[2 * ka + 1][1]));
                union { unsigned u[4]; bf16x8 v; } pt;
                pt.u[0] = dw[2 * ka][0];     pt.u[1] = dw[2 * ka][1];
                pt.u[2] = dw[2 * ka + 1][0]; pt.u[3] = dw[2 * ka + 1][1];
                accd = __builtin_amdgcn_mfma_f32_32x32x16_bf16(pt.v, vb[sub][ka], accd, 0, 0, 0);
                accp = __builtin_amdgcn_mfma_f32_32x32x16_bf16(pt.v, onesb,      accp, 0, 0, 0);
            }
        }
        asm volatile("s_waitcnt vmcnt(2)" ::: "memory");
        __builtin_amdgcn_s_barrier();
        cur += 1; if (cur == 3) cur = 0;
    }

#pragma unroll
    for (int r = 0; r < 16; ++r) {
        const int i = ib + (r & 3) + 8 * (r >> 2) + 4 * hi;
        const float o = accd[r] / accp[r];
        ao[(size_t)(b * BN_TOK + i) * CC + h * 32 + l31] = (__bf16)o;
    }
}

// -------------------------------- launch -----------------------------------
extern "C" void kernel_launch(void* const* d_in, const int* in_sizes, int n_in,
                              void* d_out, int out_size, void* d_ws, size_t ws_size,
                              hipStream_t stream)
{
    const float* x      = (const float*)d_in[0];
    const float* ln1_g  = (const float*)d_in[1];
    const float* ln1_b  = (const float*)d_in[2];
    const float* qkv_w  = (const float*)d_in[3];
    const float* scale  = (const float*)d_in[4];
    const float* proj_w = (const float*)d_in[5];
    const float* proj_b = (const float*)d_in[6];
    const float* ln2_g  = (const float*)d_in[7];
    const float* ln2_b  = (const float*)d_in[8];
    const float* fc1_w  = (const float*)d_in[9];
    const float* fc1_b  = (const float*)d_in[10];
    const float* fc2_w  = (const float*)d_in[11];
    const float* fc2_b  = (const float*)d_in[12];

    char* ws = (char*)d_ws;
    __bf16* wbf   = (__bf16*)(ws + OFF_W);
    __bf16* abf   = (__bf16*)(ws + OFF_A);
    __bf16* qkvbf = (__bf16*)(ws + OFF_QKV);
    __bf16* x1bf  = (__bf16*)(ws + OFF_QKV);   // overlays qkv after attention
    __bf16* vT    = (__bf16*)(ws + OFF_H);     // 8 MB; overwritten by hbf later
    __bf16* hbf   = (__bf16*)(ws + OFF_H);
    float*  out   = (float*)d_out;

    cvt_w_kernel<<<768, 256, 0, stream>>>(qkv_w, proj_w, fc1_w, fc2_w, wbf);
    ln_kernel<<<4096, 256, 0, stream>>>(x, ln1_g, ln1_b, abf);
    gemm_k<128,0,0,0,0,1,1><<<dim3(128,6), 256, 0, stream>>>(
        abf, wbf + WOFF_QKV, nullptr, nullptr, qkvbf, vT, MROWS, 768, 256);
    attn_kernel<<<dim3(16,64), 256, 0, stream>>>(qkvbf, vT, scale, abf);
    gemm_k<64,1,0,1,0,1,0><<<dim3(256,2), 256, 0, stream>>>(
        abf, wbf + WOFF_PRJ, proj_b, x, x1bf, nullptr, MROWS, 256, 256);
    ln_bf_kernel<<<4096, 256, 0, stream>>>(x1bf, ln2_g, ln2_b, abf);
    gemm_k<128,1,1,0,0,1,0><<<dim3(128,8), 256, 0, stream>>>(
        abf, wbf + WOFF_FC1, fc1_b, nullptr, hbf, nullptr, MROWS, HID_DIM, 256);
    gemm_k<64,1,0,1,1,0,0><<<dim3(256,2), 256, 0, stream>>>(
        hbf, wbf + WOFF_FC2, fc2_b, x1bf, out, nullptr, MROWS, 256, HID_DIM);
}

// Round 8
// 241.532 us; speedup vs baseline: 1.2477x; 1.0262x over previous
//
#include <hip/hip_runtime.h>
#include <cstdint>
#include <cstddef>

// ---------------------------------------------------------------------------
// LSA transformer block: x += attn(LN1(x)); x += MLP(LN2(x))
// B=8, N=2048, C=256, H=8, D=32, HID=1024
// ---------------------------------------------------------------------------

typedef __bf16 bf16x8 __attribute__((ext_vector_type(8)));
typedef __bf16 bf16x4 __attribute__((ext_vector_type(4)));
typedef float  f32x4  __attribute__((ext_vector_type(4)));
typedef float  f32x16 __attribute__((ext_vector_type(16)));

#define BN_TOK   2048
#define CC       256
#define HID_DIM  1024
#define MROWS    16384   // B*N

// ws layout (bytes)
#define OFF_W    0u          // 786432 bf16 weights (1.5 MB)
#define OFF_A    1572864u    // 16384x256 bf16 (8 MB): ln1/attn/ln2 out
#define OFF_QKV  9961472u    // 16384x768 bf16 (24 MB); later x1 bf16 (8 MB)
#define OFF_H    35127296u   // vT 64x32x2048 bf16 (8 MB), then hbf 16384x1024 bf16 (32 MB)
#define WOFF_QKV 0
#define WOFF_PRJ 196608
#define WOFF_FC1 262144
#define WOFF_FC2 524288

__device__ __forceinline__ void gload_lds16(const __bf16* g, __bf16* l) {
    __builtin_amdgcn_global_load_lds(
        (const __attribute__((address_space(1))) void*)g,
        (__attribute__((address_space(3))) void*)l, 16, 0, 0);
}

__device__ __forceinline__ float fexp2(float x) {
    float r;
    asm("v_exp_f32 %0, %1" : "=v"(r) : "v"(x));
    return r;
}

__device__ __forceinline__ unsigned pk2(float lo, float hi) {
    union { __bf16 b[2]; unsigned u; } t;
    t.b[0] = (__bf16)lo; t.b[1] = (__bf16)hi;
    return t.u;
}

// -------------------------------- weight cvt -------------------------------
__global__ __launch_bounds__(256) void cvt_w_kernel(
    const float* __restrict__ q, const float* __restrict__ p,
    const float* __restrict__ f1, const float* __restrict__ f2,
    __bf16* __restrict__ dst)
{
    int i = (blockIdx.x * 256 + threadIdx.x) * 4;
    const float* src; int off;
    if (i < 196608)      { src = q;  off = 0; }
    else if (i < 262144) { src = p;  off = 196608; }
    else if (i < 524288) { src = f1; off = 262144; }
    else                 { src = f2; off = 524288; }
    float4 v = *(const float4*)(src + (i - off));
    bf16x4 o;
    o[0] = (__bf16)v.x; o[1] = (__bf16)v.y; o[2] = (__bf16)v.z; o[3] = (__bf16)v.w;
    *(bf16x4*)(dst + i) = o;
}

// -------------------------------- layernorm (fp32 in) ----------------------
__global__ __launch_bounds__(256) void ln_kernel(
    const float* __restrict__ x, const float* __restrict__ g,
    const float* __restrict__ b, __bf16* __restrict__ y)
{
    const int lane = threadIdx.x & 63;
    const int row  = blockIdx.x * 4 + (threadIdx.x >> 6);
    const float4 xv = *(const float4*)(x + (size_t)row * CC + lane * 4);
    float s  = xv.x + xv.y + xv.z + xv.w;
    float s2 = xv.x*xv.x + xv.y*xv.y + xv.z*xv.z + xv.w*xv.w;
#pragma unroll
    for (int m = 1; m < 64; m <<= 1) {
        s  += __shfl_xor(s,  m);
        s2 += __shfl_xor(s2, m);
    }
    const float mean = s * (1.0f / 256.0f);
    const float var  = fmaxf(s2 * (1.0f / 256.0f) - mean * mean, 0.0f);
    const float rstd = rsqrtf(var + 1e-5f);
    const float4 gv = *(const float4*)(g + lane * 4);
    const float4 bv = *(const float4*)(b + lane * 4);
    bf16x4 o;
    o[0] = (__bf16)((xv.x - mean) * rstd * gv.x + bv.x);
    o[1] = (__bf16)((xv.y - mean) * rstd * gv.y + bv.y);
    o[2] = (__bf16)((xv.z - mean) * rstd * gv.z + bv.z);
    o[3] = (__bf16)((xv.w - mean) * rstd * gv.w + bv.w);
    *(bf16x4*)(y + (size_t)row * CC + lane * 4) = o;
}

// -------------------------------- layernorm (bf16 in) ----------------------
__global__ __launch_bounds__(256) void ln_bf_kernel(
    const __bf16* __restrict__ x, const float* __restrict__ g,
    const float* __restrict__ b, __bf16* __restrict__ y)
{
    const int lane = threadIdx.x & 63;
    const int row  = blockIdx.x * 4 + (threadIdx.x >> 6);
    const bf16x4 xv = *(const bf16x4*)&x[(size_t)row * CC + lane * 4];
    float x0 = (float)xv[0], x1 = (float)xv[1], x2 = (float)xv[2], x3 = (float)xv[3];
    float s  = x0 + x1 + x2 + x3;
    float s2 = x0*x0 + x1*x1 + x2*x2 + x3*x3;
#pragma unroll
    for (int m = 1; m < 64; m <<= 1) {
        s  += __shfl_xor(s,  m);
        s2 += __shfl_xor(s2, m);
    }
    const float mean = s * (1.0f / 256.0f);
    const float var  = fmaxf(s2 * (1.0f / 256.0f) - mean * mean, 0.0f);
    const float rstd = rsqrtf(var + 1e-5f);
    const float4 gv = *(const float4*)(g + lane * 4);
    const float4 bv = *(const float4*)(b + lane * 4);
    bf16x4 o;
    o[0] = (__bf16)((x0 - mean) * rstd * gv.x + bv.x);
    o[1] = (__bf16)((x1 - mean) * rstd * gv.y + bv.y);
    o[2] = (__bf16)((x2 - mean) * rstd * gv.z + bv.z);
    o[3] = (__bf16)((x3 - mean) * rstd * gv.w + bv.w);
    *(bf16x4*)(y + (size_t)row * CC + lane * 4) = o;
}

// -------------------------------- GEMM (pipelined, 3-buf) ------------------
// out[m][n] = sum_k A[m][k]*W[n][k] (+bias,+gelu,+res). BK=32.
// LDS rows are 64B (4 x 16B slots); slot s of row j holds global chunk
// s ^ p(j), p(j)=(j>>1)&3 -> every 8-lane phase group covers all 32 banks.
// 3-deep global_load_lds pipeline with true counted vmcnt (2 stages in flight).
template<int BM, int BIAS, int GELU, int RES, int RESBF, int OUTBF, int VSPLIT>
__global__ __launch_bounds__(256) void gemm_k(
    const __bf16* __restrict__ A, const __bf16* __restrict__ W,
    const float* __restrict__ bias, const void* __restrict__ resv,
    void* __restrict__ outp, __bf16* __restrict__ vT, int M, int N, int K)
{
    constexpr int MI  = BM / 32;       // m-frags per wave
    constexpr int ASZ = BM * 32;
    __shared__ __align__(16) __bf16 As[3 * ASZ];
    __shared__ __align__(16) __bf16 Bs[3 * 4096];
    const int tid = threadIdx.x, lane = tid & 63, wid = tid >> 6;
    const int wr = wid >> 1, wc = wid & 1;
    const int fr = lane & 15, fg = lane >> 4;
    const int tm = blockIdx.x * BM, tn = blockIdx.y * 128;

    // staging source: chunk = (lane&3) ^ p(row), p = (lane>>3)&3
    const int lrow = lane >> 2, lk = ((lane & 3) ^ ((lane >> 3) & 3)) * 8;
    const __bf16* gA = A + (size_t)(tm + (BM == 128 ? wid * 32 : wid * 16) + lrow) * K + lk;
    const __bf16* gB = W + (size_t)(tn + wid * 32 + lrow) * K + lk;
    const size_t rowK16 = (size_t)16 * K;
    const int aoff = (BM == 128 ? wid * 1024 : wid * 512);
    const int boff = wid * 1024;
    // read slot: fg ^ p(fr)
    const int rslot = (fg ^ ((fr >> 1) & 3)) * 8;

    const int KT = K >> 5;

    auto STAGE = [&](int kt, int buf) {
        const int k0 = kt * 32;
        __bf16* lA = As + buf * ASZ + aoff;
        __bf16* lB = Bs + buf * 4096 + boff;
        gload_lds16(gA + k0, lA);
        if (BM == 128) gload_lds16(gA + rowK16 + k0, lA + 512);
        gload_lds16(gB + k0, lB);
        gload_lds16(gB + rowK16 + k0, lB + 512);
    };

    f32x4 acc[MI][4];
    const f32x4 vz = {0.f, 0.f, 0.f, 0.f};
#pragma unroll
    for (int mi = 0; mi < MI; ++mi)
#pragma unroll
        for (int nj = 0; nj < 4; ++nj) acc[mi][nj] = vz;

    STAGE(0, 0);
    STAGE(1 < KT ? 1 : 0, 1);
    if (BM == 128) asm volatile("s_waitcnt vmcnt(4)" ::: "memory");
    else           asm volatile("s_waitcnt vmcnt(3)" ::: "memory");
    __builtin_amdgcn_s_barrier();

    int cur = 0;
    for (int k = 0; k < KT; ++k) {
        int nt = k + 2; if (nt > KT - 1) nt = KT - 1;
        int sb = cur + 2; if (sb >= 3) sb -= 3;
        STAGE(nt, sb);

        const __bf16* bA = As + cur * ASZ;
        const __bf16* bB = Bs + cur * 4096;
        bf16x8 af[MI], bfv[4];
#pragma unroll
        for (int mi = 0; mi < MI; ++mi)
            af[mi] = *(const bf16x8*)&bA[(wr * (BM / 2) + mi * 16 + fr) * 32 + rslot];
#pragma unroll
        for (int nj = 0; nj < 4; ++nj)
            bfv[nj] = *(const bf16x8*)&bB[(wc * 64 + nj * 16 + fr) * 32 + rslot];
#pragma unroll
        for (int mi = 0; mi < MI; ++mi)
#pragma unroll
            for (int nj = 0; nj < 4; ++nj)
                acc[mi][nj] = __builtin_amdgcn_mfma_f32_16x16x32_bf16(
                    af[mi], bfv[nj], acc[mi][nj], 0, 0, 0);

        // wait only for buffer cur+1's loads (2 stages stay in flight)
        if (BM == 128) asm volatile("s_waitcnt vmcnt(8)" ::: "memory");
        else           asm volatile("s_waitcnt vmcnt(6)" ::: "memory");
        __builtin_amdgcn_s_barrier();
        cur += 1; if (cur == 3) cur = 0;
    }
    asm volatile("s_waitcnt vmcnt(0)" ::: "memory");

    if (VSPLIT && tn >= 512) {
        // V head -> vT[bh][d][n] transposed (quad r = 4 consecutive tokens)
#pragma unroll
        for (int mi = 0; mi < MI; ++mi) {
#pragma unroll
            for (int nj = 0; nj < 4; ++nj) {
                const int dfull = tn - 512 + wc * 64 + nj * 16 + fr;   // 0..255
                const int row0  = tm + wr * (BM / 2) + mi * 16 + fg * 4;
                const int bb = row0 >> 11;
                const int n0 = row0 & 2047;
                bf16x4 pk;
                pk[0] = (__bf16)acc[mi][nj][0]; pk[1] = (__bf16)acc[mi][nj][1];
                pk[2] = (__bf16)acc[mi][nj][2]; pk[3] = (__bf16)acc[mi][nj][3];
                *(bf16x4*)&vT[((size_t)(bb * 8 + (dfull >> 5)) * 32 + (dfull & 31)) * 2048 + n0] = pk;
            }
        }
        return;
    }

#pragma unroll
    for (int mi = 0; mi < MI; ++mi) {
#pragma unroll
        for (int nj = 0; nj < 4; ++nj) {
            const int col = tn + wc * 64 + nj * 16 + fr;
            float bv = 0.0f;
            if (BIAS) bv = bias[col];
#pragma unroll
            for (int r = 0; r < 4; ++r) {
                const int row = tm + wr * (BM / 2) + mi * 16 + fg * 4 + r;
                float v = acc[mi][nj][r];
                if (BIAS) v += bv;
                if (GELU) v = v * 0.5f * (1.0f + erff(v * 0.70710678118654752f));
                if (RES) {
                    if (RESBF) v += (float)((const __bf16*)resv)[(size_t)row * N + col];
                    else       v += ((const float*)resv)[(size_t)row * N + col];
                }
                if (OUTBF) ((__bf16*)outp)[(size_t)row * N + col] = (__bf16)v;
                else       ((float*)outp)[(size_t)row * N + col]  = v;
            }
        }
    }
}

// -------------------------------- attention --------------------------------
// 32x32x16-MFMA flash attention, no-max softmax, P fully in-register
// (permlane32_swap redistribution). K tile: 64 rows x 4 slots, slot perm
// p(j)=(j>>1)&3 (phase-group bank-perfect). V^T tile: 32 rows x 8 slots,
// perm d&7. 3-buf global_load_lds pipeline, counted vmcnt(4), setprio.
__global__ __launch_bounds__(256, 4) void attn_kernel(
    const __bf16* __restrict__ qkv, const __bf16* __restrict__ vT,
    const float* __restrict__ scale_p, __bf16* __restrict__ ao)
{
    __shared__ __align__(16) __bf16 Ks[3 * 2048];
    __shared__ __align__(16) __bf16 Vs[3 * 2048];

    const int tid = threadIdx.x, lane = tid & 63, wid = tid >> 6;
    const int l31 = lane & 31, hi = lane >> 5;
    const int qt = blockIdx.x, bh = blockIdx.y;
    const int b = bh >> 3, h = bh & 7;
    const float c = scale_p[0] * 1.4426950408889634f;   // scale * log2(e)
    const size_t base = (size_t)b * BN_TOK * 768;
    const int hq = h * 32, hk = 256 + h * 32;
    const int ib = qt * 128 + wid * 32;    // wave's 32 q-rows

    // Q B-operand (col i=l31, k-chunk hi), pre-scaled by c
    const __bf16* qrow = qkv + base + (size_t)(ib + l31) * 768 + hq;
    bf16x8 qf[2];
    {
        const bf16x8 t0 = *(const bf16x8*)(qrow + hi * 8);
        const bf16x8 t1 = *(const bf16x8*)(qrow + 16 + hi * 8);
#pragma unroll
        for (int e = 0; e < 8; ++e) {
            qf[0][e] = (__bf16)((float)t0[e] * c);
            qf[1][e] = (__bf16)((float)t1[e] * c);
        }
    }
    bf16x8 onesb;
#pragma unroll
    for (int e = 0; e < 8; ++e) onesb[e] = (__bf16)1.0f;

    f32x16 accd = {};   // O[i][d]: d = l31, i = (r&3)+8*(r>>2)+4*hi
    f32x16 accp = {};   // row sums, same layout

    // staging sources (source-baked slot perms; LDS dest linear lane*16)
    const int srow = tid >> 2;
    const int kblk = ((tid & 3) ^ ((tid >> 3) & 3)) * 8;   // chunk = slot ^ p(j)
    const __bf16* ksrc = qkv + base + (size_t)srow * 768 + hk + kblk;
    const int vd = tid >> 3;
    const int vblk = ((tid & 7) ^ (vd & 7)) * 8;
    const __bf16* vsrc = vT + ((size_t)(bh * 32 + vd)) * 2048 + vblk;
    __bf16* kdw = Ks + wid * 512;
    __bf16* vdw = Vs + wid * 512;

    auto STAGE = [&](int nt, int buf) {
        gload_lds16(ksrc + (size_t)nt * 64 * 768, kdw + buf * 2048);
        gload_lds16(vsrc + nt * 64,               vdw + buf * 2048);
    };

    // hoisted LDS byte offsets
    const int koff0 = l31 * 64 + (((hi)     ^ ((l31 >> 1) & 3)) << 4);
    const int koff1 = l31 * 64 + (((2 ^ hi) ^ ((l31 >> 1) & 3)) << 4);
    int voff[2][2];
#pragma unroll
    for (int sub = 0; sub < 2; ++sub)
#pragma unroll
        for (int ka = 0; ka < 2; ++ka)
            voff[sub][ka] = l31 * 128 + (((sub * 4 + ka * 2 + hi) ^ (l31 & 7)) << 4);

    STAGE(0, 0);
    STAGE(1, 1);
    asm volatile("s_waitcnt vmcnt(2)" ::: "memory");
    __builtin_amdgcn_s_barrier();

    int cur = 0;
    for (int jt = 0; jt < 32; ++jt) {
        const int jb = jt * 64;
        int nt = jt + 2; if (nt > 31) nt = 31;
        int sb = cur + 2; if (sb >= 3) sb -= 3;
        STAGE(nt, sb);

        const char* kb   = (const char*)(Ks + cur * 2048);
        const char* vbuf = (const char*)(Vs + cur * 2048);

        bf16x8 vb[2][2];
#pragma unroll
        for (int sub = 0; sub < 2; ++sub)
#pragma unroll
            for (int ka = 0; ka < 2; ++ka)
                vb[sub][ka] = *(const bf16x8*)(vbuf + voff[sub][ka]);

#pragma unroll
        for (int sub = 0; sub < 2; ++sub) {
            const bf16x8 kf0 = *(const bf16x8*)(kb + sub * 2048 + koff0);
            const bf16x8 kf1 = *(const bf16x8*)(kb + sub * 2048 + koff1);
            f32x16 s = {};
            __builtin_amdgcn_s_setprio(1);
            s = __builtin_amdgcn_mfma_f32_32x32x16_bf16(kf0, qf[0], s, 0, 0, 0);
            s = __builtin_amdgcn_mfma_f32_32x32x16_bf16(kf1, qf[1], s, 0, 0, 0);
            __builtin_amdgcn_s_setprio(0);
#pragma unroll
            for (int r = 0; r < 16; ++r) s[r] = fexp2(s[r]);
            if (jb + sub * 32 == ib) {   // diagonal subtile: mask j==i
#pragma unroll
                for (int r = 0; r < 16; ++r)
                    if (((r & 3) + 8 * (r >> 2) + 4 * hi) == l31) s[r] = 0.f;
            }
            // pack pairs: dw[q][h] = bf16x2 of j' = 8q+4hi+2h, +1
            unsigned dw[4][2];
#pragma unroll
            for (int q = 0; q < 4; ++q)
#pragma unroll
                for (int hh = 0; hh < 2; ++hh)
                    dw[q][hh] = pk2(s[4 * q + 2 * hh], s[4 * q + 2 * hh + 1]);
#pragma unroll
            for (int ka = 0; ka < 2; ++ka) {
                asm("v_permlane32_swap_b32 %0, %1"
                    : "+v"(dw[2 * ka][0]), "+v"(dw[2 * ka + 1][0]));
                asm("v_permlane32_swap_b32 %0, %1"
                    : "+v"(dw[2 * ka][1]), "+v"(dw[2 * ka + 1][1]));
                union { unsigned u[4]; bf16x8 v; } pt;
                pt.u[0] = dw[2 * ka][0];     pt.u[1] = dw[2 * ka][1];
                pt.u[2] = dw[2 * ka + 1][0]; pt.u[3] = dw[2 * ka + 1][1];
                __builtin_amdgcn_s_setprio(1);
                accd = __builtin_amdgcn_mfma_f32_32x32x16_bf16(pt.v, vb[sub][ka], accd, 0, 0, 0);
                accp = __builtin_amdgcn_mfma_f32_32x32x16_bf16(pt.v, onesb,      accp, 0, 0, 0);
                __builtin_amdgcn_s_setprio(0);
            }
        }
        asm volatile("s_waitcnt vmcnt(4)" ::: "memory");
        __builtin_amdgcn_s_barrier();
        cur += 1; if (cur == 3) cur = 0;
    }
    asm volatile("s_waitcnt vmcnt(0)" ::: "memory");

#pragma unroll
    for (int r = 0; r < 16; ++r) {
        const int i = ib + (r & 3) + 8 * (r >> 2) + 4 * hi;
        const float o = accd[r] / accp[r];
        ao[(size_t)(b * BN_TOK + i) * CC + h * 32 + l31] = (__bf16)o;
    }
}

// -------------------------------- launch -----------------------------------
extern "C" void kernel_launch(void* const* d_in, const int* in_sizes, int n_in,
                              void* d_out, int out_size, void* d_ws, size_t ws_size,
                              hipStream_t stream)
{
    const float* x      = (const float*)d_in[0];
    const float* ln1_g  = (const float*)d_in[1];
    const float* ln1_b  = (const float*)d_in[2];
    const float* qkv_w  = (const float*)d_in[3];
    const float* scale  = (const float*)d_in[4];
    const float* proj_w = (const float*)d_in[5];
    const float* proj_b = (const float*)d_in[6];
    const float* ln2_g  = (const float*)d_in[7];
    const float* ln2_b  = (const float*)d_in[8];
    const float* fc1_w  = (const float*)d_in[9];
    const float* fc1_b  = (const float*)d_in[10];
    const float* fc2_w  = (const float*)d_in[11];
    const float* fc2_b  = (const float*)d_in[12];

    char* ws = (char*)d_ws;
    __bf16* wbf   = (__bf16*)(ws + OFF_W);
    __bf16* abf   = (__bf16*)(ws + OFF_A);
    __bf16* qkvbf = (__bf16*)(ws + OFF_QKV);
    __bf16* x1bf  = (__bf16*)(ws + OFF_QKV);   // overlays qkv after attention
    __bf16* vT    = (__bf16*)(ws + OFF_H);     // 8 MB; overwritten by hbf later
    __bf16* hbf   = (__bf16*)(ws + OFF_H);
    float*  out   = (float*)d_out;

    cvt_w_kernel<<<768, 256, 0, stream>>>(qkv_w, proj_w, fc1_w, fc2_w, wbf);
    ln_kernel<<<4096, 256, 0, stream>>>(x, ln1_g, ln1_b, abf);
    gemm_k<128,0,0,0,0,1,1><<<dim3(128,6), 256, 0, stream>>>(
        abf, wbf + WOFF_QKV, nullptr, nullptr, qkvbf, vT, MROWS, 768, 256);
    attn_kernel<<<dim3(16,64), 256, 0, stream>>>(qkvbf, vT, scale, abf);
    gemm_k<64,1,0,1,0,1,0><<<dim3(256,2), 256, 0, stream>>>(
        abf, wbf + WOFF_PRJ, proj_b, x, x1bf, nullptr, MROWS, 256, 256);
    ln_bf_kernel<<<4096, 256, 0, stream>>>(x1bf, ln2_g, ln2_b, abf);
    gemm_k<128,1,1,0,0,1,0><<<dim3(128,8), 256, 0, stream>>>(
        abf, wbf + WOFF_FC1, fc1_b, nullptr, hbf, nullptr, MROWS, HID_DIM, 256);
    gemm_k<64,1,0,1,1,0,0><<<dim3(256,2), 256, 0, stream>>>(
        hbf, wbf + WOFF_FC2, fc2_b, x1bf, out, nullptr, MROWS, 256, HID_DIM);
}